// Round 6
// baseline (165.823 us; speedup 1.0000x reference)
//
#include <hip/hip_runtime.h>
#include <math.h>

typedef __bf16 bf16x8 __attribute__((ext_vector_type(8)));
typedef float f32x16 __attribute__((ext_vector_type(16)));

#define NTOK 131072
#define HDIM 128
#define ODIM 128
#define NEXP 8

__device__ __forceinline__ unsigned short f2bf(float f){
  union { float f; unsigned u; } v; v.f = f;
  unsigned r = v.u + 0x7FFFu + ((v.u >> 16) & 1u);
  return (unsigned short)(r >> 16);
}

// ---------------------------------------------------------------------------
// Kernel 1: pack W. Layout: [ot(4)][h(2)][e(8)][kt2(4)][l(64)][j(8)] bf16.
// A-frag (v_mfma_f32_32x32x16_bf16): A[m=l&31][k=(l>>5)*8+j]; o = ot*32+(l&31);
// k_global = (h*4+kt2)*16 + (l>>5)*8 + j. Bias NOT packed (epilogue handles it).
__global__ void pack_w(const float* __restrict__ we, unsigned short* __restrict__ pw){
  int f = blockIdx.x * 256 + threadIdx.x;       // 0..16383 (16B chunk id)
  int l   = f & 63;
  int kt2 = (f >> 6) & 3;
  int e   = (f >> 8) & 7;
  int h   = (f >> 11) & 1;
  int ot  = (f >> 12) & 3;
  int o = ot * 32 + (l & 31);
  int kbase = (h * 4 + kt2) * 16 + ((l >> 5) << 3);
  unsigned short vals[8];
#pragma unroll
  for (int j = 0; j < 8; ++j)
    vals[j] = f2bf(we[(e * HDIM + kbase + j) * ODIM + o]);
  *(bf16x8*)(pw + (size_t)f * 8) = *(bf16x8*)vals;
}

// ---------------------------------------------------------------------------
// Kernel 2: gating + x->bf16-frag pack. 64 tokens/block, 256 threads.
// (unchanged from R5 — works, ~25 us, near its 100 MB data floor)
__global__ void gating_pack(const float* __restrict__ x, const float* __restrict__ wg,
                            float* __restrict__ gates_t, unsigned short* __restrict__ xf){
  __shared__ float xs[64 * 128];   // [tok][f4-chunk c ^ (tok&7)] 32 KB
  __shared__ float wgl[128 * 8];   // 4 KB
  __shared__ float plg[64 * 36];   // [tok][q*8+e], stride 36 (pad) 9 KB
  int t = threadIdx.x;
  size_t tokbase = (size_t)blockIdx.x * 64;

  ((float4*)wgl)[t] = ((const float4*)wg)[t];
  {
    const float4* xsrc = (const float4*)(x + tokbase * HDIM);
#pragma unroll
    for (int i = 0; i < 8; ++i){
      int idx = i * 256 + t;
      int tok = idx >> 5, c = idx & 31;
      *(float4*)&xs[tok * 128 + ((c ^ (tok & 7)) << 2)] = xsrc[idx];
    }
  }
  __syncthreads();

  {
    int tok = t & 63, q = t >> 6;
    float lg[8];
#pragma unroll
    for (int e = 0; e < 8; ++e) lg[e] = 0.0f;
#pragma unroll
    for (int i = 0; i < 8; ++i){
      int c = q * 8 + i;
      float4 v = *(float4*)&xs[tok * 128 + ((c ^ (tok & 7)) << 2)];
      const float* wr = wgl + c * 32;
#pragma unroll
      for (int e = 0; e < 8; ++e)
        lg[e] += v.x * wr[e] + v.y * wr[8 + e] + v.z * wr[16 + e] + v.w * wr[24 + e];
    }
    *(float4*)&plg[tok * 36 + q * 8]     = make_float4(lg[0], lg[1], lg[2], lg[3]);
    *(float4*)&plg[tok * 36 + q * 8 + 4] = make_float4(lg[4], lg[5], lg[6], lg[7]);
  }
  __syncthreads();

  if (t < 64){
    float lg[8];
#pragma unroll
    for (int e = 0; e < 8; ++e)
      lg[e] = plg[t * 36 + e] + plg[t * 36 + 8 + e] + plg[t * 36 + 16 + e] + plg[t * 36 + 24 + e];
    int i1 = 0; float v1 = lg[0];
#pragma unroll
    for (int e = 1; e < 8; ++e) if (lg[e] > v1){ v1 = lg[e]; i1 = e; }
    int i2 = -1; float v2 = -3.4e38f;
#pragma unroll
    for (int e = 0; e < 8; ++e) if (e != i1 && lg[e] > v2){ v2 = lg[e]; i2 = e; }
    float ex = __expf(v2 - v1);
    float inv = 1.0f / (1.0f + ex);
#pragma unroll
    for (int e = 0; e < 8; ++e)
      gates_t[(size_t)e * NTOK + tokbase + t] = (e == i1) ? inv : ((e == i2) ? ex * inv : 0.0f);
  }

  {
    int tokL = t >> 2, q = t & 3;
    float4 cv[8];
#pragma unroll
    for (int i = 0; i < 8; ++i)
      cv[i] = *(float4*)&xs[tokL * 128 + (((q * 8 + i) ^ (tokL & 7)) << 2)];
    size_t tgG = (size_t)blockIdx.x * 2 + (tokL >> 5);
#pragma unroll
    for (int jb = 0; jb < 4; ++jb){
      int h0 = q * 32 + jb * 8;
      int kt = h0 >> 4;
      int lslot = (tokL & 31) + 32 * (jb & 1);
      float4 a = cv[2 * jb], b = cv[2 * jb + 1];
      unsigned long long lo = (unsigned long long)f2bf(a.x)
                            | ((unsigned long long)f2bf(a.y) << 16)
                            | ((unsigned long long)f2bf(a.z) << 32)
                            | ((unsigned long long)f2bf(a.w) << 48);
      unsigned long long hi = (unsigned long long)f2bf(b.x)
                            | ((unsigned long long)f2bf(b.y) << 16)
                            | ((unsigned long long)f2bf(b.z) << 32)
                            | ((unsigned long long)f2bf(b.w) << 48);
      unsigned long long* dst = (unsigned long long*)(xf + ((tgG * 8 + kt) * 64 + lslot) * 8);
      dst[0] = lo; dst[1] = hi;
    }
  }
}

// ---------------------------------------------------------------------------
// Kernel 3: pure MFMA GEMM. Block: 1 o-tile (32 o's) x 256 tokens, 256 thr.
// Wave w: 2 token-groups. LDS = Wh 32 KB + blds 1 KB -> 33 KB.
// __launch_bounds__(256,4): 4 blocks/CU resident (R5 lesson: 2 blocks/CU left
// MFMA pipe 73% idle on barrier/latency phases). Gates read per-e from global
// (L2-resident 4 MB) instead of LDS staging. Regs ~116 < 128 cap.
// Accumulators/arrays: named vars / constant indices ONLY (R1-R3 scratch lesson).
__launch_bounds__(256, 4)
__global__ void moe_gemm(const unsigned short* __restrict__ pw,
                         const unsigned short* __restrict__ xf,
                         const float* __restrict__ gates_t,
                         const float* __restrict__ be, float* __restrict__ out){
  __shared__ unsigned short Wh[16384];   // 32 KB: [e8][kt2(4)][l64][j8]
  __shared__ float blds[256];            //  1 KB: [e8][o32]

  int t = threadIdx.x;
  int ot = blockIdx.x & 3;
  int tb = blockIdx.x >> 2;              // 0..511
  int w = t >> 6, l = t & 63, l32 = l & 31, lh = l >> 5;
  size_t tokb = (size_t)tb * 256;

  blds[t] = be[(t >> 5) * ODIM + ot * 32 + (t & 31)];

  f32x16 zero16;
#pragma unroll
  for (int i = 0; i < 16; ++i) zero16[i] = 0.0f;
  f32x16 tot0 = zero16, tot1 = zero16;

#pragma unroll 1
  for (int h = 0; h < 2; ++h){
    // stage W-half (coalesced 16B chunks, 32 KB)
    {
      const uint4* wsrc = (const uint4*)(pw + (size_t)(ot * 2 + h) * 16384);
      uint4* wdst = (uint4*)Wh;
#pragma unroll
      for (int it = 0; it < 8; ++it)
        wdst[it * 256 + t] = wsrc[it * 256 + t];
    }
    // x B-frags -> regs (1 KB contiguous per wave-load)
    bf16x8 xb0[4], xb1[4];
    {
      size_t tgG = tokb / 32 + w * 2;
#pragma unroll
      for (int kt = 0; kt < 4; ++kt){
        xb0[kt] = *(const bf16x8*)(xf + (((tgG + 0) * 8 + h * 4 + kt) * 64 + l) * 8);
        xb1[kt] = *(const bf16x8*)(xf + (((tgG + 1) * 8 + h * 4 + kt) * 64 + l) * 8);
      }
    }
    __syncthreads();   // Wh ready

#pragma unroll 1
    for (int e = 0; e < 8; ++e){
      float g0 = gates_t[(size_t)e * NTOK + tokb + (w * 2 + 0) * 32 + l32];
      float g1 = gates_t[(size_t)e * NTOK + tokb + (w * 2 + 1) * 32 + l32];
      f32x16 p0 = zero16, p1 = zero16;
#pragma unroll
      for (int kt = 0; kt < 4; ++kt){
        bf16x8 a = *(const bf16x8*)&Wh[((e * 4 + kt) * 64 + l) * 8];
        p0 = __builtin_amdgcn_mfma_f32_32x32x16_bf16(a, xb0[kt], p0, 0, 0, 0);
        p1 = __builtin_amdgcn_mfma_f32_32x32x16_bf16(a, xb1[kt], p1, 0, 0, 0);
      }
#pragma unroll
      for (int r = 0; r < 16; ++r){ tot0[r] += g0 * p0[r]; tot1[r] += g1 * p1[r]; }
    }
    __syncthreads();   // e-loop LDS reads done before h=1 re-stage
  }

  // epilogue: bias (b_expert weighted by gates) + direct stores.
  // C/D map: token(col) = l32, o = ot*32 + rg*8 + lh*4 + rr  (r = rg*4+rr)
#pragma unroll
  for (int e = 0; e < 8; ++e){
    float g0 = gates_t[(size_t)e * NTOK + tokb + (w * 2 + 0) * 32 + l32];
    float g1 = gates_t[(size_t)e * NTOK + tokb + (w * 2 + 1) * 32 + l32];
#pragma unroll
    for (int rg = 0; rg < 4; ++rg){
      float4 b4 = *(float4*)&blds[e * 32 + rg * 8 + lh * 4];
      tot0[rg * 4 + 0] += g0 * b4.x; tot0[rg * 4 + 1] += g0 * b4.y;
      tot0[rg * 4 + 2] += g0 * b4.z; tot0[rg * 4 + 3] += g0 * b4.w;
      tot1[rg * 4 + 0] += g1 * b4.x; tot1[rg * 4 + 1] += g1 * b4.y;
      tot1[rg * 4 + 2] += g1 * b4.z; tot1[rg * 4 + 3] += g1 * b4.w;
    }
  }
  {
    float* orow0 = out + (tokb + (size_t)(w * 2 + 0) * 32 + l32) * ODIM + ot * 32;
    float* orow1 = out + (tokb + (size_t)(w * 2 + 1) * 32 + l32) * ODIM + ot * 32;
#pragma unroll
    for (int rg = 0; rg < 4; ++rg){
      *(float4*)(orow0 + rg * 8 + lh * 4) =
        make_float4(tot0[rg * 4 + 0], tot0[rg * 4 + 1], tot0[rg * 4 + 2], tot0[rg * 4 + 3]);
      *(float4*)(orow1 + rg * 8 + lh * 4) =
        make_float4(tot1[rg * 4 + 0], tot1[rg * 4 + 1], tot1[rg * 4 + 2], tot1[rg * 4 + 3]);
    }
  }
}

// ---------------------------------------------------------------------------
extern "C" void kernel_launch(void* const* d_in, const int* in_sizes, int n_in,
                              void* d_out, int out_size, void* d_ws, size_t ws_size,
                              hipStream_t stream){
  const float* x  = (const float*)d_in[0];
  const float* wg = (const float*)d_in[1];
  // d_in[2] = w_noise (inactive in eval mode)
  const float* we = (const float*)d_in[3];
  const float* be = (const float*)d_in[4];
  // d_in[5] = top_k (== 2, baked in)
  float* out = (float*)d_out;

  unsigned short* pw      = (unsigned short*)d_ws;                    // 256 KB
  float*          gates_t = (float*)((char*)d_ws + 262144);           // 4 MB
  unsigned short* xf      = (unsigned short*)((char*)d_ws + 4456448); // 32 MB

  pack_w     <<<64,   256, 0, stream>>>(we, pw);
  gating_pack<<<2048, 256, 0, stream>>>(x, wg, gates_t, xf);
  moe_gemm   <<<2048, 256, 0, stream>>>(pw, xf, gates_t, be, out);
}